// Round 10
// baseline (95.631 us; speedup 1.0000x reference)
//
#include <hip/hip_runtime.h>
#include <hip/hip_fp16.h>

#define N_SYM 50000
#define N_DIS 10000
#define F_IN 128
#define HID 128
#define OUTF 64
#define NE 640000
#define NEG_SLOPE 0.2f

#define SPAN 128          // nodes per bin (== k_fuse tile)
#define NB 391            // ceil(N_SYM / SPAN)
#define SUBS 16           // sub-regions per bin (blockIdx&15: XCD-pure mod 8)
#define SCAP 192          // per-region capacity: mean 102, +9 sigma (deterministic, no drops)
#define CURSTRIDE 16      // ints: one cursor per 64B line (atomic line throughput)
#define NREG (NB * SUBS)  // 6256 regions
#define LCAP 48           // per-node bucket capacity: P(Poisson(12.8)>48) ~ 1e-12
#define HSTR 144          // LDS tile row stride in halves: 288B = 16B-aligned, 4-way banks

#define AR_BLOCKS 6250    // N_SYM*32/256
#define PROJ_BLOCKS 625   // N_DIS/16

typedef _Float16 f16x8 __attribute__((ext_vector_type(8)));
typedef float f32x4 __attribute__((ext_vector_type(4)));

// ---- K0: v_dst = Wdst_ds @ adst_ds (block 0) + zero bin cursors (all blocks) ----
__global__ __launch_bounds__(256) void k_pre(const float* __restrict__ Wd,
                                             const float* __restrict__ ad,
                                             float* __restrict__ v_dst,
                                             int* __restrict__ bcur) {
    int tid = threadIdx.x;
    for (int i = blockIdx.x * 256 + tid; i < NREG * CURSTRIDE; i += 64 * 256)
        bcur[i] = 0;
    if (blockIdx.x == 0) {
        int k = tid >> 1;                     // output 0..127
        int hh = tid & 1;
        const float4* Wr = (const float4*)(Wd + k * HID + hh * 64);
        const float4* av = (const float4*)(ad + hh * 64);
        float s = 0.f;
#pragma unroll
        for (int j = 0; j < 16; ++j) {
            float4 w = Wr[j], xx = av[j];
            s += w.x * xx.x + w.y * xx.y + w.z * xx.z + w.w * xx.w;
        }
        s += __shfl_xor(s, 1);
        if (!hh) v_dst[k] = s;
    }
}

// ---- K1 merged: blocks 0..6249: ar2 dot + dense bin-scatter
//                 blocks 6250..6874: h16 = fp16(x_dis @ Wsrc_ds) + al2 fused
#define R1 16
__global__ __launch_bounds__(256) void k_main(const float* __restrict__ x_sym,
                                              const float* __restrict__ x_dis,
                                              const int* __restrict__ esrc,
                                              const int* __restrict__ edst,
                                              const float* __restrict__ Wsrc,
                                              const float* __restrict__ asrc,
                                              const float* __restrict__ v_dst,
                                              __half* __restrict__ h16,
                                              float* __restrict__ al2,
                                              float* __restrict__ ar2,
                                              int* __restrict__ bcur,
                                              unsigned int* __restrict__ bins) {
    int tid = threadIdx.x;
    if (blockIdx.x < AR_BLOCKS) {
        int gid = blockIdx.x * 256 + tid;
        if (gid < NE) {
            int s = esrc[gid];
            int d = edst[gid];
            int region = (s >> 7) * SUBS + (blockIdx.x & (SUBS - 1));
            unsigned int v = ((unsigned int)(s & 127) << 14) | (unsigned int)d;
            int pos = atomicAdd(&bcur[region * CURSTRIDE], 1);
            if (pos < SCAP) bins[region * SCAP + pos] = v;
        }
        int r = gid >> 5;
        int l = tid & 31;
        if (r >= N_SYM) return;
        float4 hv = *(const float4*)(x_sym + r * F_IN + l * 4);
        float4 av = *(const float4*)(v_dst + l * 4);
        float s = hv.x * av.x + hv.y * av.y + hv.z * av.z + hv.w * av.w;
#pragma unroll
        for (int m = 16; m; m >>= 1) s += __shfl_xor(s, m);
        if (!l) ar2[r] = s;
        return;
    }
    // ---- projection part ----
    int pblk = blockIdx.x - AR_BLOCKS;        // 0..624
    __shared__ float xl[R1 * F_IN];
    int rowbase = pblk * R1;
    const float4* src = (const float4*)(x_dis + rowbase * F_IN);
    float4* dl = (float4*)xl;
    for (int i = tid; i < R1 * F_IN / 4; i += 256) dl[i] = src[i];
    __syncthreads();
    int c2 = tid & 63;   // column pair: cols 2*c2, 2*c2+1
    int rg = tid >> 6;   // 0..3 -> rows rg+4i
    float acc[4][2] = {};
    for (int k = 0; k < F_IN; ++k) {
        float2 w = *(const float2*)(Wsrc + k * HID + c2 * 2);
#pragma unroll
        for (int i = 0; i < 4; ++i) {
            float xv = xl[(rg + 4 * i) * F_IN + k];
            acc[i][0] += xv * w.x;
            acc[i][1] += xv * w.y;
        }
    }
    __half2* h2 = (__half2*)h16;
    float2 av = *(const float2*)(asrc + 2 * c2);
#pragma unroll
    for (int i = 0; i < 4; ++i) {
        h2[(rowbase + rg + 4 * i) * 64 + c2] = __floats2half2_rn(acc[i][0], acc[i][1]);
        float p = acc[i][0] * av.x + acc[i][1] * av.y;   // al2 partial
#pragma unroll
        for (int m = 32; m; m >>= 1) p += __shfl_xor(p, m);
        if (c2 == 0) al2[rowbase + rg + 4 * i] = p;
    }
}

// ---- K2 fused: per-bin build (LDS) -> agg (LDS tile) -> MFMA final GEMM ----
__device__ __forceinline__ void acc_row(float4& acc, float2 rr, float ww) {
    __half2 a01 = *(__half2*)&rr.x;
    __half2 a23 = *(__half2*)&rr.y;
    float2 f01 = __half22float2(a01), f23 = __half22float2(a23);
    acc.x += ww * f01.x;
    acc.y += ww * f01.y;
    acc.z += ww * f23.x;
    acc.w += ww * f23.y;
}

__global__ __launch_bounds__(512) void k_fuse(const unsigned int* __restrict__ bins,
                                              const int* __restrict__ bcur,
                                              const float* __restrict__ al2,
                                              const float* __restrict__ ar2,
                                              const __half* __restrict__ h16,
                                              const float* __restrict__ b_ds,
                                              const float* __restrict__ lin_W,
                                              const float* __restrict__ lin_b,
                                              float* __restrict__ out) {
    __shared__ int lcount[SPAN];
    __shared__ unsigned short lb[SPAN * LCAP];              // 12.3 KB
    __shared__ __align__(16) _Float16 htile[SPAN][HSTR];    // 36.9 KB
    __shared__ __align__(16) _Float16 BT[OUTF][HSTR];       // 18.4 KB
    __shared__ float bias[OUTF];
    int tid = threadIdx.x;
    int bin = blockIdx.x;
    int nodebase = bin * SPAN;
    int nnodes = min(SPAN, N_SYM - nodebase);
    for (int i = tid; i < SPAN; i += 512) lcount[i] = 0;
    for (int idx = tid; idx < HID * OUTF; idx += 512) {
        int k = idx >> 6, c = idx & 63;
        BT[c][k] = (_Float16)lin_W[idx];
    }
    if (tid < OUTF) bias[tid] = lin_b[tid];
    __syncthreads();
    // ---- phase A: rank edges into LDS buckets (one half-wave per sub-region) ----
    {
        int hw = tid >> 5;          // 0..15 == sub
        int hl = tid & 31;
        int region = bin * SUBS + hw;
        int n = bcur[region * CURSTRIDE];
        if (n > SCAP) n = SCAP;
        const unsigned int* base = bins + region * SCAP;
        for (int i = hl; i < n; i += 32) {
            unsigned int v = base[i];
            int sl = v >> 14;
            int d = v & 0x3FFF;
            int rank = atomicAdd(&lcount[sl], 1);
            if (rank < LCAP) lb[sl * LCAP + rank] = (unsigned short)d;
        }
    }
    __syncthreads();
    // ---- phase B: softmax + weighted gather, 32 lanes/node, 8 passes of 16 nodes ----
    int wave = tid >> 6, lane = tid & 63, half = lane >> 5, l = lane & 31;
    const float2* hb = (const float2*)h16;   // row d -> units d*32 + l
    for (int p = 0; p < 8; ++p) {
        int nl = p * 16 + wave * 2 + half;   // uniform across the 32-lane group
        if (nl >= nnodes) continue;
        int dg = min(lcount[nl], LCAP);
        int off = nl * LCAP;
        float arn = ar2[nodebase + nl];
        int di = 0;
        float lv = -1e30f;
        if (l < dg) {
            di = lb[off + l];
            float t = al2[di] + arn;
            lv = (t > 0.f) ? t : NEG_SLOPE * t;
        }
        float mm = lv;
        for (int i = 32 + l; i < dg; i += 32) {        // rare tail (dg in 33..48)
            float t = al2[lb[off + i]] + arn;
            t = (t > 0.f) ? t : NEG_SLOPE * t;
            mm = fmaxf(mm, t);
        }
#pragma unroll
        for (int s = 16; s; s >>= 1) mm = fmaxf(mm, __shfl_xor(mm, s, 32));
        float4 acc = make_float4(0.f, 0.f, 0.f, 0.f);
        float den = 0.f;                     // w lane-uniform: no reduce needed
        int dgc = dg < 32 ? dg : 32;
        int e = 0;
        for (; e + 4 <= dgc; e += 4) {
            int d0 = __shfl(di, e + 0, 32); float w0 = __expf(__shfl(lv, e + 0, 32) - mm);
            int d1 = __shfl(di, e + 1, 32); float w1 = __expf(__shfl(lv, e + 1, 32) - mm);
            int d2 = __shfl(di, e + 2, 32); float w2 = __expf(__shfl(lv, e + 2, 32) - mm);
            int d3 = __shfl(di, e + 3, 32); float w3 = __expf(__shfl(lv, e + 3, 32) - mm);
            float2 r0 = hb[d0 * 32 + l];
            float2 r1 = hb[d1 * 32 + l];
            float2 r2 = hb[d2 * 32 + l];
            float2 r3 = hb[d3 * 32 + l];
            den += w0 + w1 + w2 + w3;
            acc_row(acc, r0, w0);
            acc_row(acc, r1, w1);
            acc_row(acc, r2, w2);
            acc_row(acc, r3, w3);
        }
        for (; e < dgc; ++e) {
            int d = __shfl(di, e, 32);
            float w = __expf(__shfl(lv, e, 32) - mm);
            float2 r = hb[d * 32 + l];
            den += w;
            acc_row(acc, r, w);
        }
        for (int i = 32; i < dg; ++i) {               // rare tail
            int dd = lb[off + i];
            float t = al2[dd] + arn;
            t = (t > 0.f) ? t : NEG_SLOPE * t;
            float w = __expf(t - mm);
            float2 r = hb[dd * 32 + l];
            den += w;
            acc_row(acc, r, w);
        }
        float inv = (dg > 0) ? 1.f / den : 0.f;
        float4 bv = *(const float4*)(b_ds + l * 4);
        __half2 o01 = __floats2half2_rn(fmaxf(acc.x * inv + bv.x, 0.f),
                                        fmaxf(acc.y * inv + bv.y, 0.f));
        __half2 o23 = __floats2half2_rn(fmaxf(acc.z * inv + bv.z, 0.f),
                                        fmaxf(acc.w * inv + bv.w, 0.f));
        float2 pack;
        *(__half2*)&pack.x = o01;
        *(__half2*)&pack.y = o23;
        *(float2*)&htile[nl][l * 4] = pack;   // relu(h_sym) row in LDS
    }
    __syncthreads();
    // ---- phase C: out[tile] = htile @ BT^T + bias via MFMA, 16 rows/wave ----
    int rowloc = wave * 16 + (lane & 15);
    int kbase = (lane >> 4) * 8;
    f16x8 a[4];
#pragma unroll
    for (int kc = 0; kc < 4; ++kc)
        a[kc] = *(const f16x8*)(&htile[rowloc][kc * 32 + kbase]);
#pragma unroll
    for (int ct = 0; ct < 4; ++ct) {
        int bcol = ct * 16 + (lane & 15);
        f32x4 acc = {0.f, 0.f, 0.f, 0.f};
#pragma unroll
        for (int kc = 0; kc < 4; ++kc) {
            f16x8 bf = *(const f16x8*)(&BT[bcol][kc * 32 + kbase]);
            acc = __builtin_amdgcn_mfma_f32_16x16x32_f16(a[kc], bf, acc, 0, 0, 0);
        }
        int r0 = wave * 16 + (lane >> 4) * 4;
        float bc = bias[bcol];
#pragma unroll
        for (int r = 0; r < 4; ++r) {
            int rl = r0 + r;
            if (rl < nnodes) out[(nodebase + rl) * OUTF + bcol] = acc[r] + bc;
        }
    }
}

extern "C" void kernel_launch(void* const* d_in, const int* in_sizes, int n_in,
                              void* d_out, int out_size, void* d_ws, size_t ws_size,
                              hipStream_t stream) {
    const float* x_sym   = (const float*)d_in[0];
    const float* x_dis   = (const float*)d_in[1];
    const int*   esrc    = (const int*)d_in[2];
    const int*   edst    = (const int*)d_in[3];
    // d_in[4..8] = sym->dis GAT params: DEAD CODE (h_dis never used)
    const float* Wsrc_ds = (const float*)d_in[9];
    const float* Wdst_ds = (const float*)d_in[10];
    const float* asrc_ds = (const float*)d_in[11];
    const float* adst_ds = (const float*)d_in[12];
    const float* b_ds    = (const float*)d_in[13];
    const float* lin_W   = (const float*)d_in[14];
    const float* lin_b   = (const float*)d_in[15];
    float* out = (float*)d_out;

    // workspace layout (~10 MB)
    float*  ws     = (float*)d_ws;
    float*  v_dst  = ws;                      // 128
    float*  al2    = v_dst + 128;             // N_DIS
    float*  ar2    = al2 + N_DIS;             // N_SYM
    int*    bcur   = (int*)(ar2 + N_SYM);     // NREG*CURSTRIDE ints (400 KB)
    unsigned int* bins = (unsigned int*)(bcur + NREG * CURSTRIDE); // NREG*SCAP (4.8 MB)
    __half* h16    = (__half*)(bins + NREG * SCAP);                // N_DIS*HID (2.56 MB)

    k_pre<<<64, 256, 0, stream>>>(Wdst_ds, adst_ds, v_dst, bcur);
    k_main<<<AR_BLOCKS + PROJ_BLOCKS, 256, 0, stream>>>(x_sym, x_dis, esrc, edst,
                                                        Wsrc_ds, asrc_ds, v_dst,
                                                        h16, al2, ar2, bcur, bins);
    k_fuse<<<NB, 512, 0, stream>>>(bins, bcur, al2, ar2, h16, b_ds,
                                   lin_W, lin_b, out);
}